// Round 1
// baseline (856.629 us; speedup 1.0000x reference)
//
#include <hip/hip_runtime.h>
#include <hip/hip_fp16.h>

typedef _Float16 f16;
typedef _Float16 f16x8 __attribute__((ext_vector_type(8)));
typedef _Float16 f16x2 __attribute__((ext_vector_type(2)));
typedef float f32x4 __attribute__((ext_vector_type(4)));

static constexpr int kB  = 16;
static constexpr int kLC = 512;
static constexpr int kLQ = 64;
static constexpr int kD  = 256;
static constexpr int kH  = 256;

// ---------------- helpers ----------------
__device__ __forceinline__ float sigm(float x) { return 1.f / (1.f + __expf(-x)); }
__device__ __forceinline__ float tanhfast(float x) {
  float xc = fminf(fmaxf(x, -15.f), 15.f);
  float e = __expf(2.f * xc);
  return (e - 1.f) / (e + 1.f);
}
// async global->LDS, 16B per lane; LDS dest = wave-uniform base + lane*16
__device__ __forceinline__ void load_lds_16(const void* g, void* l) {
  __builtin_amdgcn_global_load_lds(
      (const __attribute__((address_space(1))) void*)g,
      (__attribute__((address_space(3))) void*)(unsigned)(unsigned long long)l,
      16, 0, 0);
}
__device__ __forceinline__ float dot2f(unsigned a, unsigned b, float c) {
#if __has_builtin(__builtin_amdgcn_fdot2)
  return __builtin_amdgcn_fdot2(__builtin_bit_cast(f16x2, a),
                                __builtin_bit_cast(f16x2, b), c, false);
#else
  f16x2 av = __builtin_bit_cast(f16x2, a);
  f16x2 bv = __builtin_bit_cast(f16x2, b);
  return fmaf((float)av.x, (float)bv.x, fmaf((float)av.y, (float)bv.y, c));
#endif
}
__device__ __forceinline__ unsigned packh2(float a, float b) {
  union { f16 h[2]; unsigned u; } x;
  x.h[0] = (f16)a; x.h[1] = (f16)b;
  return x.u;
}

// ---------------- conversion kernels ----------------
__global__ void cvt_flat(const float* __restrict__ in, f16* __restrict__ out, int n) {
  int i = blockIdx.x * 256 + threadIdx.x;
  if (i < n) out[i] = (f16)in[i];
}
// context [8192,256] -> left half of rnn_h [8192,512]
__global__ void cvt_ctx(const float* __restrict__ in, f16* __restrict__ out) {
  int i = blockIdx.x * 256 + threadIdx.x;          // i < 8192*256
  int r = i >> 8, c = i & 255;
  out[r * 512 + c] = (f16)in[i];
}
// in [R][C] f32 -> out [C][R] f16 (transpose + convert)
__global__ void cvt_tr(const float* __restrict__ in, f16* __restrict__ out, int R, int C) {
  __shared__ float t[32][33];
  int nbc = C >> 5;
  int c0 = (blockIdx.x % nbc) << 5;
  int r0 = (blockIdx.x / nbc) << 5;
  int tx = threadIdx.x & 31, ty = threadIdx.x >> 5;   // 32 x 8
  #pragma unroll
  for (int rr = 0; rr < 32; rr += 8)
    t[ty + rr][tx] = in[(size_t)(r0 + ty + rr) * C + c0 + tx];
  __syncthreads();
  #pragma unroll
  for (int rr = 0; rr < 32; rr += 8)
    out[(size_t)(c0 + ty + rr) * R + r0 + tx] = (f16)t[tx][ty + rr];
}

// ---------------- MFMA f16 GEMM (m97-style, 128x128 tile, BK=32) ----------------
// A [M,K] f16 rows (lda), B [N,K] f16 rows (ldb)  ->  C[M,N]
// EPI 0: Cf[row*N+col] = acc + bias[col]           (f32 store)
// EPI 1: Ch[row*N+col] = f16( Gin[row*N+col] * sigmoid(acc + bias[col]) )
template <int EPI>
__global__ __launch_bounds__(256, 2) void gemm_nt(
    const f16* __restrict__ A, int lda,
    const f16* __restrict__ B, int ldb,
    const float* __restrict__ bias,
    float* __restrict__ Cf, f16* __restrict__ Ch, const f16* __restrict__ Gin,
    int M, int N, int K) {
  __shared__ f16 As[2][128 * 32];
  __shared__ f16 Bs[2][128 * 32];
  const int tiles_n = N >> 7;
  const int bm = (blockIdx.x / tiles_n) << 7;
  const int bn = (blockIdx.x % tiles_n) << 7;
  const int tid = threadIdx.x, wv = tid >> 6, lane = tid & 63;
  const int lr = lane & 15, lk = lane >> 4;
  const int wm = (wv >> 1) << 6, wn = (wv & 1) << 6;
  const int srow = lane >> 2;            // 0..15 within 16-row chunk
  const int scol = (lane & 3) << 3;      // 0,8,16,24 (f16 elements)
  f32x4 acc[4][4] = {};

  auto stage = [&](int buf, int kt) {
    const int k0 = kt << 5;
    #pragma unroll
    for (int c = 0; c < 2; ++c) {
      const int row = ((wv * 2 + c) << 4) + srow;
      load_lds_16(A + (size_t)(bm + row) * lda + k0 + scol,
                  &As[buf][(wv * 2 + c) * 512]);
      load_lds_16(B + (size_t)(bn + row) * ldb + k0 + scol,
                  &Bs[buf][(wv * 2 + c) * 512]);
    }
  };

  const int NT = K >> 5;
  stage(0, 0);
  for (int kt = 0; kt < NT; ++kt) {
    const int buf = kt & 1;
    __syncthreads();                       // drains vmcnt -> buf staged, all waves synced
    if (kt + 1 < NT) stage(buf ^ 1, kt + 1);
    f16x8 af[4], bf[4];
    #pragma unroll
    for (int i = 0; i < 4; ++i)
      af[i] = *(const f16x8*)&As[buf][(wm + i * 16 + lr) * 32 + lk * 8];
    #pragma unroll
    for (int i = 0; i < 4; ++i)
      bf[i] = *(const f16x8*)&Bs[buf][(wn + i * 16 + lr) * 32 + lk * 8];
    #pragma unroll
    for (int mi = 0; mi < 4; ++mi)
      #pragma unroll
      for (int ni = 0; ni < 4; ++ni)
        acc[mi][ni] = __builtin_amdgcn_mfma_f32_16x16x32_f16(af[mi], bf[ni], acc[mi][ni], 0, 0, 0);
    __syncthreads();                       // done reading buf before it is restaged
  }

  // epilogue: C/D layout col=lane&15, row=(lane>>4)*4+reg  [guide §3, m89/m91]
  const int crow0 = bm + wm + lk * 4;
  const int ccol0 = bn + wn + lr;
  #pragma unroll
  for (int mi = 0; mi < 4; ++mi) {
    #pragma unroll
    for (int ni = 0; ni < 4; ++ni) {
      const int col = ccol0 + ni * 16;
      const float bv = bias[col];
      #pragma unroll
      for (int j = 0; j < 4; ++j) {
        const int row = crow0 + mi * 16 + j;
        const float v = acc[mi][ni][j] + bv;
        if constexpr (EPI == 0) {
          Cf[(size_t)row * N + col] = v;
        } else {
          const float rin = (float)Gin[(size_t)row * N + col];
          Ch[(size_t)row * N + col] = (f16)(rin * sigm(v));
        }
      }
    }
  }
}

// ---------------- fused additive attention ----------------
// score[p,q] = bs + sum_h Ws[h]*tanh(cd[p,h]+qd[q,h]);  softmax over q;
// att[p,d] = sum_q sim[q]*qrep[q,d]  -> written as f16 into rnn_h[:, 256:512]
__global__ __launch_bounds__(256) void attn_kernel(
    const float* __restrict__ cd, const float* __restrict__ qd,
    const float* __restrict__ qrep, const float* __restrict__ Ws,
    const float* __restrict__ bsp, const float* __restrict__ qmask,
    f16* __restrict__ rnn_h) {
  const int b = blockIdx.x >> 4;
  const int pc = blockIdx.x & 15;
  __shared__ f16 qd_s[64][264];   // padded: bank-spread
  __shared__ float ws_s[256];
  __shared__ float cd_s[256];
  __shared__ float sc_s[64];
  __shared__ float msk[64];
  const int tid = threadIdx.x;
  const float* qdb = qd + (size_t)b * 64 * 256;
  for (int i = tid; i < 64 * 256; i += 256) qd_s[i >> 8][i & 255] = (f16)qdb[i];
  ws_s[tid] = Ws[tid];
  if (tid < 64) msk[tid] = qmask[b * 64 + tid];
  __syncthreads();
  const float bsv = bsp[0];
  const float* qr = qrep + (size_t)b * 64 * 256;
  const int q = tid >> 2, l4 = tid & 3;
  for (int pi = 0; pi < 32; ++pi) {
    const int p = (pc << 5) + pi;
    cd_s[tid] = cd[((size_t)b * 512 + p) * 256 + tid];
    __syncthreads();
    // score: thread (q, l4) covers h = l4*4 + e + 16*jj
    float s = 0.f;
    #pragma unroll 2
    for (int jj = 0; jj < 16; ++jj) {
      const int h0 = (l4 << 2) + (jj << 4);
      #pragma unroll
      for (int e = 0; e < 4; ++e) {
        const int hh = h0 + e;
        s += ws_s[hh] * tanhfast(cd_s[hh] + (float)qd_s[q][hh]);
      }
    }
    s += __shfl_xor(s, 1);
    s += __shfl_xor(s, 2);
    if (l4 == 0) sc_s[q] = (msk[q] > 0.f) ? (s + bsv) : -1e30f;
    __syncthreads();
    // softmax over 64 by wave 0
    if (tid < 64) {
      float v = sc_s[tid], m = v;
      #pragma unroll
      for (int o = 32; o; o >>= 1) m = fmaxf(m, __shfl_xor(m, o));
      const float e = __expf(v - m);
      float su = e;
      #pragma unroll
      for (int o = 32; o; o >>= 1) su += __shfl_xor(su, o);
      sc_s[tid] = e / su;
    }
    __syncthreads();
    // att: thread d = tid
    float a = 0.f;
    #pragma unroll 8
    for (int q2 = 0; q2 < 64; ++q2) a = fmaf(sc_s[q2], qr[q2 * 256 + tid], a);
    rnn_h[(((size_t)b * 512 + p) << 9) + 256 + tid] = (f16)a;
  }
}

// ---------------- GRU: one block per batch, Whh f16 in VGPRs, v_dot2 ----------------
__global__ __launch_bounds__(768, 3) void gru_kernel(
    const float* __restrict__ xp_all, const f16* __restrict__ Whh_h,
    const float* __restrict__ bhh, const int* __restrict__ clen,
    float* __restrict__ out) {
  const int b = blockIdx.x;
  const float* xp = xp_all + (size_t)b * 512 * 768;
  float* ob = out + (size_t)b * 512 * 256;
  const int j = threadIdx.x;           // 0..767, owns row j of Whh
  uint4 wreg[32];                       // 256 f16 = row j of Whh
  {
    const uint4* wr = (const uint4*)(Whh_h + (size_t)j * 256);
    #pragma unroll
    for (int u = 0; u < 32; ++u) wreg[u] = wr[u];
  }
  const float bj = bhh[j];
  __shared__ unsigned h2[128];          // h as f16x2
  __shared__ float hp_s[768];
  if (j < 128) h2[j] = 0u;
  float h = 0.f;
  const int len = clen[b];
  __syncthreads();
  for (int t = 0; t < 512; ++t) {
    float xr = 0.f, xz = 0.f, xn = 0.f;
    if (j < 256) {                      // issue early; latency hides under dots
      xr = xp[t * 768 + j];
      xz = xp[t * 768 + 256 + j];
      xn = xp[t * 768 + 512 + j];
    }
    float hp = bj;
    #pragma unroll
    for (int u = 0; u < 32; ++u) {
      const uint4 hv = ((const uint4*)h2)[u];   // LDS broadcast
      hp = dot2f(wreg[u].x, hv.x, hp);
      hp = dot2f(wreg[u].y, hv.y, hp);
      hp = dot2f(wreg[u].z, hv.z, hp);
      hp = dot2f(wreg[u].w, hv.w, hp);
    }
    hp_s[j] = hp;
    __syncthreads();                    // dots done before h2 is rewritten
    if (j < 256) {
      const float r = sigm(xr + hp_s[j]);
      const float z = sigm(xz + hp_s[256 + j]);
      const float n = tanhfast(xn + r * hp_s[512 + j]);
      h = (1.f - z) * n + z * h;
      ob[t * 256 + j] = (t < len) ? h : 0.f;
      const float ho = __shfl_xor(h, 1);
      if ((j & 1) == 0) h2[j >> 1] = packh2(h, ho);
    }
    __syncthreads();                    // h2(t) visible before next step's dots
  }
}

// ---------------- launch ----------------
extern "C" void kernel_launch(void* const* d_in, const int* in_sizes, int n_in,
                              void* d_out, int out_size, void* d_ws, size_t ws_size,
                              hipStream_t stream) {
  const float* ctx   = (const float*)d_in[0];
  const float* qrep  = (const float*)d_in[1];
  const int*   clen  = (const int*)d_in[2];
  const float* qmask = (const float*)d_in[3];
  const float* Wc    = (const float*)d_in[4];
  const float* bc    = (const float*)d_in[5];
  const float* Wq    = (const float*)d_in[6];
  const float* bq    = (const float*)d_in[7];
  const float* Ws    = (const float*)d_in[8];
  const float* bs    = (const float*)d_in[9];
  const float* Wg    = (const float*)d_in[10];
  const float* bg    = (const float*)d_in[11];
  const float* Wih   = (const float*)d_in[12];
  const float* Whh   = (const float*)d_in[13];
  const float* bih   = (const float*)d_in[14];
  const float* bhh   = (const float*)d_in[15];
  float* out = (float*)d_out;

  char* w = (char*)d_ws;
  auto alloc = [&](size_t bytes) -> void* {
    void* p = (void*)w;
    w += (bytes + 255) & ~(size_t)255;
    return p;
  };
  const int M = kB * kLC;                 // 8192
  float* cd    = (float*)alloc((size_t)M * 256 * 4);
  float* qd    = (float*)alloc((size_t)1024 * 256 * 4);
  float* xproj = (float*)alloc((size_t)M * 768 * 4);
  f16* rnn_h   = (f16*)alloc((size_t)M * 512 * 2);
  f16* q_h     = (f16*)alloc((size_t)1024 * 256 * 2);
  f16* g_h     = (f16*)alloc((size_t)M * 512 * 2);
  f16* Wct_h   = (f16*)alloc((size_t)256 * 256 * 2);
  f16* Wqt_h   = (f16*)alloc((size_t)256 * 256 * 2);
  f16* Wgt_h   = (f16*)alloc((size_t)512 * 512 * 2);
  f16* Wih_h   = (f16*)alloc((size_t)768 * 512 * 2);
  f16* Whh_h   = (f16*)alloc((size_t)768 * 256 * 2);

  // conversions
  cvt_ctx <<<M, 256, 0, stream>>>(ctx, rnn_h);
  cvt_flat<<<1024, 256, 0, stream>>>(qrep, q_h, 1024 * 256);
  cvt_flat<<<1536, 256, 0, stream>>>(Wih, Wih_h, 768 * 512);
  cvt_flat<<<768, 256, 0, stream>>>(Whh, Whh_h, 768 * 256);
  cvt_tr  <<<64, 256, 0, stream>>>(Wc, Wct_h, 256, 256);
  cvt_tr  <<<64, 256, 0, stream>>>(Wq, Wqt_h, 256, 256);
  cvt_tr  <<<256, 256, 0, stream>>>(Wg, Wgt_h, 512, 512);

  // cd = ctx @ Wc + bc ; qd = q @ Wq + bq
  gemm_nt<0><<<(M / 128) * (256 / 128), 256, 0, stream>>>(
      rnn_h, 512, Wct_h, 256, bc, cd, nullptr, nullptr, M, 256, 256);
  gemm_nt<0><<<(1024 / 128) * (256 / 128), 256, 0, stream>>>(
      q_h, 256, Wqt_h, 256, bq, qd, nullptr, nullptr, 1024, 256, 256);

  // attention -> rnn_h[:, 256:512]
  attn_kernel<<<256, 256, 0, stream>>>(cd, qd, qrep, Ws, bs, qmask, rnn_h);

  // g = rnn_in * sigmoid(rnn_in @ Wg + bg)   (f16 out)
  gemm_nt<1><<<(M / 128) * (512 / 128), 256, 0, stream>>>(
      rnn_h, 512, Wgt_h, 512, bg, nullptr, g_h, rnn_h, M, 512, 512);

  // x_proj = g @ Wih.T + bih   (f32 out)
  gemm_nt<0><<<(M / 128) * (768 / 128), 256, 0, stream>>>(
      g_h, 512, Wih_h, 512, bih, xproj, nullptr, nullptr, M, 768, 512);

  // GRU + output masking
  gru_kernel<<<kB, 768, 0, stream>>>(xproj, Whh_h, bhh, clen, out);
}